// Round 9
// baseline (951.804 us; speedup 1.0000x reference)
//
#include <hip/hip_runtime.h>

#define N_NODES 30000
#define DFEAT 128
#define HID 64
#define G4 256

typedef __bf16 bfrag __attribute__((ext_vector_type(8)));
typedef float f32x4 __attribute__((ext_vector_type(4)));
typedef float f32x2 __attribute__((ext_vector_type(2)));

#define SC_SIG -1.442695041f
#define SC_TANH -2.885390082f

__device__ inline float bflo(unsigned u){ return __builtin_bit_cast(float, u << 16); }
__device__ inline float bfhi(unsigned u){ return __builtin_bit_cast(float, u & 0xFFFF0000u); }
__device__ inline unsigned short bf16u(float a){
  unsigned ua = __builtin_bit_cast(unsigned, a);
  ua += 0x7FFFu + ((ua >> 16) & 1u);
  return (unsigned short)(ua >> 16);
}
// native f32->bf16 (RNE)
__device__ inline unsigned short bfn(float a){
  return __builtin_bit_cast(unsigned short, (__bf16)a);
}
__device__ inline unsigned packbf(float a, float b){
  unsigned ua = __builtin_bit_cast(unsigned, a);
  unsigned ub = __builtin_bit_cast(unsigned, b);
  ua += 0x7FFFu + ((ua >> 16) & 1u);
  ub += 0x7FFFu + ((ub >> 16) & 1u);
  return (ua >> 16) | (ub & 0xFFFF0000u);
}
__device__ inline bfrag ldfrag(const unsigned short* p){
  return *reinterpret_cast<const bfrag*>(p);
}
__device__ inline f32x4 mfma16(bfrag a, bfrag b, f32x4 c){
  return __builtin_amdgcn_mfma_f32_16x16x32_bf16(a, b, c, 0, 0, 0);
}
// nbr_idx dtype probe (confirmed int32 in prior session, kept at zero cost)
__device__ inline int idx_stride(const int* p){
  int lane = threadIdx.x & 63;
  int v = p[lane];
  int ok = (lane & 1) ? (v == 0) : (v >= 0 && v < N_NODES);
  unsigned long long m = __ballot(ok);
  int st = (m == ~0ull) ? 2 : 1;
  return __builtin_amdgcn_readfirstlane(st);
}

// LSTM elementwise on PRE-SCALED gates, row-PAIR form.
//   NUMERICS ARE BIT-IDENTICAL to the verified scalar lstm_step (R4, absmax
//   4.88e-4): every exp2 and every rcp is SCALAR with the exact same argument
//   per element.  Only the pure add/mul/fma algebra is packed into f32x2 so
//   the compiler can emit v_pk_fma_f32 / v_pk_add_f32 (full-rate, 2 vals/inst).
//   (R5's failure was cross-element PAIRED rcp — 1.4e-2 absmax. Never re-pair
//   reciprocals across elements.)
//   Per value: 5 exp2 + 2 rcp.
__device__ inline f32x2 lstm_pk(f32x2 gi, f32x2 gf, f32x2 gg, f32x2 go,
                                f32x2& cst, f32x2& hsum)
{
  f32x2 ei, ef, eg;
  ei.x = __builtin_amdgcn_exp2f(gi.x); ei.y = __builtin_amdgcn_exp2f(gi.y);
  ef.x = __builtin_amdgcn_exp2f(gf.x); ef.y = __builtin_amdgcn_exp2f(gf.y);
  eg.x = __builtin_amdgcn_exp2f(gg.x); eg.y = __builtin_amdgcn_exp2f(gg.y);
  f32x2 one = {1.f, 1.f}, two = {2.f, 2.f};
  f32x2 a = ei + one, b = eg + one, f1 = ef + one;
  f32x2 ab = a * b;
  f32x2 num = __builtin_elementwise_fma(cst, ab, (two - b) * f1);
  f32x2 den = ab * f1;
  f32x2 cn;
  cn.x = num.x * __builtin_amdgcn_rcpf(den.x);   // scalar rcp per element
  cn.y = num.y * __builtin_amdgcn_rcpf(den.y);
  cst = cn;
  f32x2 eo, ec;
  eo.x = __builtin_amdgcn_exp2f(go.x); eo.y = __builtin_amdgcn_exp2f(go.y);
  f32x2 targ = cn * SC_TANH;
  ec.x = __builtin_amdgcn_exp2f(targ.x); ec.y = __builtin_amdgcn_exp2f(targ.y);
  f32x2 o1 = eo + one, c1 = ec + one;
  f32x2 num2 = two - c1;
  f32x2 den2 = o1 * c1;
  f32x2 h;
  h.x = num2.x * __builtin_amdgcn_rcpf(den2.x);
  h.y = num2.y * __builtin_amdgcn_rcpf(den2.y);
  hsum += h;
  return h;
}

// Packed-weight segment offsets (in unsigned shorts) inside pk:
//   WihC: [2 dir][4 c][4 q][4 w][64 lane][8]   at 0       (65536)
//   WhhC: [2 dir][4 c][2 q][4 w][64 lane][8]   at 65536   (32768)
//   WihN: [6 sd ][4 c][4 q][4 w][64 lane][8]   at 98304   (196608)
//   WhhN: [6 sd ][4 c][2 q][4 w][64 lane][8]   at 294912  (98304)
// Weights are PRE-SCALED by the per-gate exp2 constants (see lstm_pk).
#define PK_WHHC 65536
#define PK_WIHN 98304
#define PK_WHHN 294912

// ---------------- Kernel P: one-time weight pack (f32 -> bf16 frag layout) ---
__global__ __launch_bounds__(256) void k_pack(
    const float* __restrict__ Wih_c, const float* __restrict__ Whh_c,
    const float* __restrict__ Wih_n, const float* __restrict__ Whh_n,
    unsigned short* __restrict__ pk)
{
  const int m = blockIdx.y;
  const float* src; unsigned short* dst; int ndir, Q;
  if (m == 0){ src = Wih_c; dst = pk;            ndir = 2; Q = 4; }
  else if (m == 1){ src = Whh_c; dst = pk + PK_WHHC; ndir = 2; Q = 2; }
  else if (m == 2){ src = Wih_n; dst = pk + PK_WIHN; ndir = 6; Q = 4; }
  else { src = Whh_n; dst = pk + PK_WHHN; ndir = 6; Q = 2; }
  const int per = Q * 8192;            // elems per dir: 4c * Q * 4w * 64 * 8
  const int total = ndir * per;
  int e = blockIdx.x * 256 + threadIdx.x;
  if (e >= total) return;
  int sd = e / per, r = e % per;
  int c = r / (Q * 2048); int r2 = r % (Q * 2048);
  int q = r2 / 2048;      int r3 = r2 % 2048;
  int w = r3 >> 9; int lane = (r3 >> 3) & 63; int j = r3 & 7;
  int gate = c * 64 + w * 16 + (lane & 15);
  int col  = q * 32 + (lane >> 4) * 8 + j;
  int D = Q * 32;
  float sc = (c == 2) ? SC_TANH : SC_SIG;   // gate order i,f,g,o
  dst[e] = bf16u(src[((size_t)sd * G4 + gate) * D + col] * sc);
}

// ---------------- Kernel A: content bi-LSTM (T=3, BOTH dirs) + fused Gtab ----
// grid (1875, 3): tile, s.  Each block runs dir0 then dir1 sequentially,
// accumulates the 16-node content tile in LDS, then computes k_gtab's
// 2 sd x 16 MFMA epilogue directly.
__global__ __launch_bounds__(256) void k_content(
    const float* __restrict__ xa, const float* __restrict__ xb,
    const float* __restrict__ xc,
    const unsigned short* __restrict__ pk,
    const float* __restrict__ bih, const float* __restrict__ bhh,
    const float* __restrict__ bih_n, const float* __restrict__ bhh_n,
    unsigned short* __restrict__ content,
    unsigned int* __restrict__ Gtab)
{
  const int tile = blockIdx.x, s = blockIdx.y;
  const float* xs = (s == 0) ? xa : ((s == 1) ? xb : xc);
  const int n0 = tile * 16;
  __shared__ __align__(16) unsigned int xdw[48 * 68];
  __shared__ __align__(16) unsigned short hbuf[2][16 * 72];
  __shared__ __align__(16) unsigned short ctile[16][136];   // padded stride
  const int tid = threadIdx.x;
  const float2* xg2 = reinterpret_cast<const float2*>(xs + (size_t)n0 * 384);
  for (int i = tid; i < 3072; i += 256){
    int node = i / 192, rem = i % 192; int t = rem / 64, c2 = rem % 64;
    float2 v = xg2[i];
    xdw[(t * 16 + node) * 68 + c2] = packbf(v.x, v.y);
  }

  const int lane = tid & 63, w = tid >> 6;
  const int nl = lane & 15, kg = lane >> 4;

  for (int dir = 0; dir < 2; ++dir){
    for (int i = tid; i < 1152; i += 256) hbuf[0][i] = 0;
    __syncthreads();   // covers x staging (iter 0) and hbuf[0] zeroing

    const unsigned short* pkWih = pk + dir * 32768;
    const unsigned short* pkWhh = pk + PK_WHHC + dir * 16384;
    bfrag Bw[4][4], Bh[4][2];
    float bias[4];
    #pragma unroll
    for (int c = 0; c < 4; ++c){
      int gate = c * 64 + w * 16 + nl;
      #pragma unroll
      for (int q = 0; q < 4; ++q)
        Bw[c][q] = ldfrag(pkWih + (((c * 4 + q) * 4 + w) * 64 + lane) * 8);
      Bh[c][0] = ldfrag(pkWhh + (((c * 2 + 0) * 4 + w) * 64 + lane) * 8);
      Bh[c][1] = ldfrag(pkWhh + (((c * 2 + 1) * 4 + w) * 64 + lane) * 8);
      float sc = (c == 2) ? SC_TANH : SC_SIG;
      bias[c] = (bih[dir * G4 + gate] + bhh[dir * G4 + gate]) * sc;
    }

    f32x2 cst2[2] = {f32x2{0,0}, f32x2{0,0}};
    f32x2 hsum2[2] = {f32x2{0,0}, f32x2{0,0}};
    int pp = 0;
    #pragma unroll
    for (int t = 0; t < 3; ++t){
      int tt = dir ? (2 - t) : t;
      f32x4 acc[4];
      #pragma unroll
      for (int c = 0; c < 4; ++c){ f32x4 bv = {bias[c], bias[c], bias[c], bias[c]}; acc[c] = bv; }
      const unsigned short* xrow = reinterpret_cast<const unsigned short*>(&xdw[(tt * 16 + nl) * 68]);
      bfrag ax[4];
      #pragma unroll
      for (int q = 0; q < 4; ++q) ax[q] = ldfrag(xrow + q * 32 + kg * 8);
      #pragma unroll
      for (int c = 0; c < 4; ++c){
        #pragma unroll
        for (int q = 0; q < 4; ++q) acc[c] = mfma16(ax[q], Bw[c][q], acc[c]);
      }
      const unsigned short* hrow = &hbuf[pp][nl * 72];
      bfrag ah0 = ldfrag(hrow + kg * 8);
      bfrag ah1 = ldfrag(hrow + 32 + kg * 8);
      #pragma unroll
      for (int c = 0; c < 4; ++c){
        acc[c] = mfma16(ah0, Bh[c][0], acc[c]);
        acc[c] = mfma16(ah1, Bh[c][1], acc[c]);
      }
      // reads of hbuf[pp] precede writes to hbuf[pp^1]; one barrier publishes.
      #pragma unroll
      for (int p = 0; p < 2; ++p){
        f32x2 gi = {acc[0][2*p], acc[0][2*p+1]};
        f32x2 gf = {acc[1][2*p], acc[1][2*p+1]};
        f32x2 gg = {acc[2][2*p], acc[2][2*p+1]};
        f32x2 go = {acc[3][2*p], acc[3][2*p+1]};
        f32x2 h = lstm_pk(gi, gf, gg, go, cst2[p], hsum2[p]);
        hbuf[pp ^ 1][(kg * 4 + 2*p) * 72 + (w * 16 + nl)]     = bfn(h.x);
        hbuf[pp ^ 1][(kg * 4 + 2*p + 1) * 72 + (w * 16 + nl)] = bfn(h.y);
      }
      __syncthreads();
      pp ^= 1;
    }
    #pragma unroll
    for (int r = 0; r < 4; ++r){
      int n = n0 + kg * 4 + r;
      float hv = (r & 1) ? hsum2[r >> 1].y : hsum2[r >> 1].x;
      unsigned short h16 = bfn(hv * (1.f / 3.f));
      content[((size_t)s * N_NODES + n) * DFEAT + dir * 64 + w * 16 + nl] = h16;
      ctile[kg * 4 + r][dir * 64 + w * 16 + nl] = h16;
    }
    // next dir's hbuf zeroing + its barrier provide the needed sync
  }
  __syncthreads();   // publish ctile for the gtab epilogue

  // ---- fused k_gtab epilogue: Gtab[sd] for sd in {2s, 2s+1} ----
  const unsigned short* crow = &ctile[nl][0];
  bfrag a[4];
  #pragma unroll
  for (int q = 0; q < 4; ++q) a[q] = ldfrag(crow + q * 32 + kg * 8);
  #pragma unroll
  for (int dd = 0; dd < 2; ++dd){
    const int sd = s * 2 + dd;
    const unsigned short* pkW = pk + PK_WIHN + sd * 32768;
    f32x4 acc[4];
    #pragma unroll
    for (int c = 0; c < 4; ++c){
      int gate = c * 64 + w * 16 + nl;
      float sc = (c == 2) ? SC_TANH : SC_SIG;
      float b = (bih_n[sd * G4 + gate] + bhh_n[sd * G4 + gate]) * sc;
      f32x4 bv = {b, b, b, b};
      acc[c] = bv;
    }
    #pragma unroll
    for (int c = 0; c < 4; ++c){
      #pragma unroll
      for (int q = 0; q < 4; ++q){
        bfrag bw = ldfrag(pkW + (((c * 4 + q) * 4 + w) * 64 + lane) * 8);
        acc[c] = mfma16(a[q], bw, acc[c]);
      }
    }
    uint2* g2 = reinterpret_cast<uint2*>(Gtab + (size_t)sd * N_NODES * 128);
    #pragma unroll
    for (int r = 0; r < 4; ++r){
      int n = n0 + kg * 4 + r;
      uint2 v;
      v.x = packbf(acc[0][r], acc[1][r]);
      v.y = packbf(acc[2][r], acc[3][r]);
      g2[(size_t)n * 64 + (w * 16 + nl)] = v;
    }
  }
}

// ---------------- Kernel C: neighbor bi-LSTM, BOTH dirs in one 512-thr block -
// Waves 0-3 = dir0, waves 4-7 = dir1 (same s,d): the dirs share idxb (loaded
// once) and proceed in lockstep t, so each of the 10 per-timestep barriers now
// serves 2x the work (R8 measured ~27% stall from barrier frequency).
// Per-wave code/registers identical to the proven R8 kernel (VGPR ~64).
// dparam >= 0: blockIdx.y = s (looped mode). dparam < 0: y in [0,9).
// R7 lesson: never request waves/EU that force VGPR+AGPR below the ~90-reg
// working set — (512,4) caps at 128 regs, same as the proven (256,4).
__global__ __launch_bounds__(512, 4) void k_neigh(
    const unsigned int* __restrict__ Gtab,
    const unsigned short* __restrict__ pk,
    const int* __restrict__ nbr_idx,
    int dparam, size_t nstride,
    unsigned short* __restrict__ nbuf)
{
  const int tile = blockIdx.x;
  int s, d;
  if (dparam < 0){ s = blockIdx.y % 3; d = blockIdx.y / 3; }
  else { s = blockIdx.y; d = dparam; }
  unsigned short* nb = nbuf + ((dparam < 0) ? (size_t)d * nstride : (size_t)0);
  const int n0 = tile * 16;
  __shared__ int idxb[160];
  __shared__ __align__(16) unsigned short hbuf[2][2][16 * 72];  // [pp][dir][...]
  const int tid = threadIdx.x;
  const int st = idx_stride(nbr_idx);
  const size_t ibase = ((size_t)(s * 3 + d) * N_NODES + n0) * 10;
  // pre-scaled to uint2-row offsets (ridx*64) so gather addr is one 32-bit add
  if (tid < 160) idxb[tid] = nbr_idx[(ibase + tid) * st] * 64;
  {
    unsigned short* hz = &hbuf[0][0][0];
    for (int i = tid; i < 2304; i += 512) hz[i] = 0;
  }
  __syncthreads();
  const int lane = tid & 63, wq = tid >> 6;
  const int w = wq & 3, dir = wq >> 2;
  const int nl = lane & 15, kg = lane >> 4;
  const int lo = w * 16 + nl;
  const int sd = s * 2 + dir;
  const unsigned short* pkW = pk + PK_WHHN + sd * 16384;
  bfrag Bh[4][2];
  #pragma unroll
  for (int c = 0; c < 4; ++c){
    Bh[c][0] = ldfrag(pkW + (((c * 2 + 0) * 4 + w) * 64 + lane) * 8);
    Bh[c][1] = ldfrag(pkW + (((c * 2 + 1) * 4 + w) * 64 + lane) * 8);
  }
  const uint2* gt2 = reinterpret_cast<const uint2*>(Gtab + (size_t)sd * N_NODES * 128);
  uint2 gn[4];
  {
    int ke = dir ? 9 : 0;
    #pragma unroll
    for (int r = 0; r < 4; ++r){
      unsigned off = (unsigned)idxb[(kg * 4 + r) * 10 + ke] + lo;
      gn[r] = gt2[off];
    }
  }
  f32x2 cst2[2] = {f32x2{0,0}, f32x2{0,0}};
  f32x2 hsum2[2] = {f32x2{0,0}, f32x2{0,0}};
  int pp = 0;
  #pragma unroll
  for (int t = 0; t < 10; ++t){
    uint2 cur[4];
    #pragma unroll
    for (int r = 0; r < 4; ++r) cur[r] = gn[r];
    if (t < 9){
      int ke = dir ? (8 - t) : (t + 1);
      #pragma unroll
      for (int r = 0; r < 4; ++r){
        unsigned off = (unsigned)idxb[(kg * 4 + r) * 10 + ke] + lo;
        gn[r] = gt2[off];
      }
    }
    f32x4 acc[4];
    #pragma unroll
    for (int r = 0; r < 4; ++r){
      acc[0][r] = bflo(cur[r].x); acc[1][r] = bfhi(cur[r].x);
      acc[2][r] = bflo(cur[r].y); acc[3][r] = bfhi(cur[r].y);
    }
    const unsigned short* hrow = &hbuf[pp][dir][nl * 72];
    bfrag ah0 = ldfrag(hrow + kg * 8);
    bfrag ah1 = ldfrag(hrow + 32 + kg * 8);
    #pragma unroll
    for (int c = 0; c < 4; ++c){
      acc[c] = mfma16(ah0, Bh[c][0], acc[c]);
      acc[c] = mfma16(ah1, Bh[c][1], acc[c]);
    }
    #pragma unroll
    for (int p = 0; p < 2; ++p){
      f32x2 gi = {acc[0][2*p], acc[0][2*p+1]};
      f32x2 gf = {acc[1][2*p], acc[1][2*p+1]};
      f32x2 gg = {acc[2][2*p], acc[2][2*p+1]};
      f32x2 go = {acc[3][2*p], acc[3][2*p+1]};
      f32x2 h = lstm_pk(gi, gf, gg, go, cst2[p], hsum2[p]);
      hbuf[pp ^ 1][dir][(kg * 4 + 2*p) * 72 + (w * 16 + nl)]     = bfn(h.x);
      hbuf[pp ^ 1][dir][(kg * 4 + 2*p + 1) * 72 + (w * 16 + nl)] = bfn(h.y);
    }
    __syncthreads();
    pp ^= 1;
  }
  #pragma unroll
  for (int r = 0; r < 4; ++r){
    int n = n0 + kg * 4 + r;
    float hv = (r & 1) ? hsum2[r >> 1].y : hsum2[r >> 1].x;
    nb[((size_t)s * N_NODES + n) * DFEAT + dir * 64 + w * 16 + nl] = bfn(hv * 0.1f);
  }
}

// ---------------- Kernel D: attention fusion; output f32 ---------------------
// dparam >= 0: d fixed (looped mode). dparam < 0: d = blockIdx.y, nbuf sliced.
__global__ __launch_bounds__(256) void k_attn(
    const unsigned short* __restrict__ content,
    const unsigned short* __restrict__ nbuf,
    const float* __restrict__ attn_w,
    const float* __restrict__ attn_b,
    int dparam, size_t nstride,
    float* __restrict__ out)
{
  const int d = (dparam < 0) ? (int)blockIdx.y : dparam;
  const unsigned short* nb = nbuf + ((dparam < 0) ? (size_t)d * nstride : (size_t)0);
  const int n = blockIdx.x * 4 + (threadIdx.x >> 6);
  const int lane = threadIdx.x & 63;
  const unsigned int* dh = reinterpret_cast<const unsigned int*>(content) + ((size_t)d * N_NODES + n) * 64;
  const float2* awv = reinterpret_cast<const float2*>(attn_w + d * 256);
  unsigned int udh = dh[lane];
  unsigned int ue[3];
  #pragma unroll
  for (int s_ = 0; s_ < 3; ++s_){
    const unsigned int* np_ = reinterpret_cast<const unsigned int*>(nb) + ((size_t)s_ * N_NODES + n) * 64;
    ue[s_] = np_[lane];
  }
  float2 wl = awv[lane], wh = awv[64 + lane];
  float dh0 = bflo(udh), dh1 = bfhi(udh);
  float p[5];
  p[4] = wl.x * dh0 + wl.y * dh1;
  #pragma unroll
  for (int k = 0; k < 3; ++k){
    p[k] = wh.x * bflo(ue[k]) + wh.y * bfhi(ue[k]);
  }
  p[3] = wh.x * dh0 + wh.y * dh1;
  #pragma unroll
  for (int m = 1; m < 64; m <<= 1){
    #pragma unroll
    for (int jj = 0; jj < 5; ++jj) p[jj] += __shfl_xor(p[jj], m, 64);
  }
  float bias = attn_b[d];
  float logit[4];
  #pragma unroll
  for (int k = 0; k < 4; ++k){
    float x = p[4] + p[k] + bias;
    logit[k] = x > 0.f ? x : 0.01f * x;
  }
  float mx = fmaxf(fmaxf(logit[0], logit[1]), fmaxf(logit[2], logit[3]));
  float ek[4], Z = 0.f;
  #pragma unroll
  for (int k = 0; k < 4; ++k){ ek[k] = __builtin_amdgcn_exp2f(1.442695041f * (logit[k] - mx)); Z += ek[k]; }
  float rz = __builtin_amdgcn_rcpf(Z);
  float o0 = 0.f, o1 = 0.f;
  #pragma unroll
  for (int k = 0; k < 3; ++k){
    float wk = ek[k] * rz;
    o0 += wk * bflo(ue[k]); o1 += wk * bfhi(ue[k]);
  }
  float w3 = ek[3] * rz;
  o0 += w3 * dh0; o1 += w3 * dh1;
  float2 res; res.x = o0; res.y = o1;
  reinterpret_cast<float2*>(out)[((size_t)d * N_NODES + n) * 64 + lane] = res;
}

extern "C" void kernel_launch(void* const* d_in, const int* in_sizes, int n_in,
                              void* d_out, int out_size, void* d_ws, size_t ws_size,
                              hipStream_t stream)
{
  const float* xa    = (const float*)d_in[0];
  const float* xb    = (const float*)d_in[1];
  const float* xc    = (const float*)d_in[2];
  const float* Wih_c = (const float*)d_in[3];
  const float* Whh_c = (const float*)d_in[4];
  const float* bih_c = (const float*)d_in[5];
  const float* bhh_c = (const float*)d_in[6];
  const float* Wih_n = (const float*)d_in[7];
  const float* Whh_n = (const float*)d_in[8];
  const float* bih_n = (const float*)d_in[9];
  const float* bhh_n = (const float*)d_in[10];
  const float* attn_w = (const float*)d_in[11];
  const float* attn_b = (const float*)d_in[12];
  const int*   nbr   = (const int*)d_in[13];
  float* out = (float*)d_out;

  // Fused-d mode needs: content 23.04MB + Gtab 92.16MB + nbuf*3 69.12MB + pk 0.79MB
  const size_t SZ_CONTENT = 23040000;
  const size_t SZ_GTAB    = 92160000;
  const size_t SZ_NBUF    = 23040000;   // one d-slice (3 s * 30000 * 128 * 2B)
  const size_t NSTRIDE    = SZ_NBUF / 2; // in ushorts
  const bool fused = ws_size >= (SZ_CONTENT + SZ_GTAB + 3 * SZ_NBUF + 786432);

  char* ws = (char*)d_ws;
  unsigned short* content = (unsigned short*)ws;
  unsigned int*   Gtab    = (unsigned int*)(ws + SZ_CONTENT);
  unsigned short* nbuf    = (unsigned short*)(ws + SZ_CONTENT + SZ_GTAB);
  unsigned short* pkw     = (unsigned short*)(ws + SZ_CONTENT + SZ_GTAB
                                                 + (fused ? 3 : 1) * SZ_NBUF);

  k_pack<<<dim3(768, 4), 256, 0, stream>>>(Wih_c, Whh_c, Wih_n, Whh_n, pkw);
  k_content<<<dim3(1875, 3), 256, 0, stream>>>(xa, xb, xc, pkw, bih_c, bhh_c,
                                               bih_n, bhh_n, content, Gtab);
  if (fused){
    k_neigh<<<dim3(1875, 9), 512, 0, stream>>>(Gtab, pkw, nbr, -1, NSTRIDE, nbuf);
    k_attn<<<dim3(7500, 3), 256, 0, stream>>>(content, nbuf, attn_w, attn_b, -1, NSTRIDE, out);
  } else {
    for (int d = 0; d < 3; ++d){
      k_neigh<<<dim3(1875, 3), 512, 0, stream>>>(Gtab, pkw, nbr, d, 0, nbuf);
      k_attn<<<dim3(7500), 256, 0, stream>>>(content, nbuf, attn_w, attn_b, d, 0, out);
    }
  }
}

// Round 11
// 792.912 us; speedup vs baseline: 1.2004x; 1.2004x over previous
//
#include <hip/hip_runtime.h>

#define N_NODES 30000
#define DFEAT 128
#define HID 64
#define G4 256

typedef __bf16 bfrag __attribute__((ext_vector_type(8)));
typedef float f32x4 __attribute__((ext_vector_type(4)));
typedef float f32x2 __attribute__((ext_vector_type(2)));

#define SC_SIG -1.442695041f
#define SC_TANH -2.885390082f

__device__ inline float bflo(unsigned u){ return __builtin_bit_cast(float, u << 16); }
__device__ inline float bfhi(unsigned u){ return __builtin_bit_cast(float, u & 0xFFFF0000u); }
__device__ inline unsigned short bf16u(float a){
  unsigned ua = __builtin_bit_cast(unsigned, a);
  ua += 0x7FFFu + ((ua >> 16) & 1u);
  return (unsigned short)(ua >> 16);
}
// native f32->bf16 (RNE)
__device__ inline unsigned short bfn(float a){
  return __builtin_bit_cast(unsigned short, (__bf16)a);
}
__device__ inline unsigned packbf(float a, float b){
  unsigned ua = __builtin_bit_cast(unsigned, a);
  unsigned ub = __builtin_bit_cast(unsigned, b);
  ua += 0x7FFFu + ((ua >> 16) & 1u);
  ub += 0x7FFFu + ((ub >> 16) & 1u);
  return (ua >> 16) | (ub & 0xFFFF0000u);
}
__device__ inline bfrag ldfrag(const unsigned short* p){
  return *reinterpret_cast<const bfrag*>(p);
}
__device__ inline f32x4 mfma16(bfrag a, bfrag b, f32x4 c){
  return __builtin_amdgcn_mfma_f32_16x16x32_bf16(a, b, c, 0, 0, 0);
}
// LDS-only barrier: drains ds_writes (the cross-wave hbuf dependency) but
// leaves global-gather vmcnt OUTSTANDING across the barrier.  __syncthreads
// emits s_waitcnt vmcnt(0) lgkmcnt(0) and would serialize the t+1 prefetch
// gathers into every step (the classic barrier-drain stall).  The compiler
// still inserts its own vmcnt(N) wait where the gather results are consumed.
__device__ inline void barrier_lds_only(){
  asm volatile("s_waitcnt lgkmcnt(0)\n\ts_barrier" ::: "memory");
}
// nbr_idx dtype probe (confirmed int32 in prior session, kept at zero cost)
__device__ inline int idx_stride(const int* p){
  int lane = threadIdx.x & 63;
  int v = p[lane];
  int ok = (lane & 1) ? (v == 0) : (v >= 0 && v < N_NODES);
  unsigned long long m = __ballot(ok);
  int st = (m == ~0ull) ? 2 : 1;
  return __builtin_amdgcn_readfirstlane(st);
}

// LSTM elementwise on PRE-SCALED gates, row-PAIR form.
//   NUMERICS ARE BIT-IDENTICAL to the verified scalar lstm_step (R4, absmax
//   4.88e-4): every exp2 and every rcp is SCALAR with the exact same argument
//   per element.  Only the pure add/mul/fma algebra is packed into f32x2 so
//   the compiler can emit v_pk_fma_f32 / v_pk_add_f32 (full-rate, 2 vals/inst).
//   (R5's failure was cross-element PAIRED rcp — 1.4e-2 absmax. Never re-pair
//   reciprocals across elements.)
//   Per value: 5 exp2 + 2 rcp.
__device__ inline f32x2 lstm_pk(f32x2 gi, f32x2 gf, f32x2 gg, f32x2 go,
                                f32x2& cst, f32x2& hsum)
{
  f32x2 ei, ef, eg;
  ei.x = __builtin_amdgcn_exp2f(gi.x); ei.y = __builtin_amdgcn_exp2f(gi.y);
  ef.x = __builtin_amdgcn_exp2f(gf.x); ef.y = __builtin_amdgcn_exp2f(gf.y);
  eg.x = __builtin_amdgcn_exp2f(gg.x); eg.y = __builtin_amdgcn_exp2f(gg.y);
  f32x2 one = {1.f, 1.f}, two = {2.f, 2.f};
  f32x2 a = ei + one, b = eg + one, f1 = ef + one;
  f32x2 ab = a * b;
  f32x2 num = __builtin_elementwise_fma(cst, ab, (two - b) * f1);
  f32x2 den = ab * f1;
  f32x2 cn;
  cn.x = num.x * __builtin_amdgcn_rcpf(den.x);   // scalar rcp per element
  cn.y = num.y * __builtin_amdgcn_rcpf(den.y);
  cst = cn;
  f32x2 eo, ec;
  eo.x = __builtin_amdgcn_exp2f(go.x); eo.y = __builtin_amdgcn_exp2f(go.y);
  f32x2 targ = cn * SC_TANH;
  ec.x = __builtin_amdgcn_exp2f(targ.x); ec.y = __builtin_amdgcn_exp2f(targ.y);
  f32x2 o1 = eo + one, c1 = ec + one;
  f32x2 num2 = two - c1;
  f32x2 den2 = o1 * c1;
  f32x2 h;
  h.x = num2.x * __builtin_amdgcn_rcpf(den2.x);
  h.y = num2.y * __builtin_amdgcn_rcpf(den2.y);
  hsum += h;
  return h;
}

// Packed-weight segment offsets (in unsigned shorts) inside pk:
//   WihC: [2 dir][4 c][4 q][4 w][64 lane][8]   at 0       (65536)
//   WhhC: [2 dir][4 c][2 q][4 w][64 lane][8]   at 65536   (32768)
//   WihN: [6 sd ][4 c][4 q][4 w][64 lane][8]   at 98304   (196608)
//   WhhN: [6 sd ][4 c][2 q][4 w][64 lane][8]   at 294912  (98304)
// Weights are PRE-SCALED by the per-gate exp2 constants (see lstm_pk).
#define PK_WHHC 65536
#define PK_WIHN 98304
#define PK_WHHN 294912

// ---------------- Kernel P: one-time weight pack (f32 -> bf16 frag layout) ---
__global__ __launch_bounds__(256) void k_pack(
    const float* __restrict__ Wih_c, const float* __restrict__ Whh_c,
    const float* __restrict__ Wih_n, const float* __restrict__ Whh_n,
    unsigned short* __restrict__ pk)
{
  const int m = blockIdx.y;
  const float* src; unsigned short* dst; int ndir, Q;
  if (m == 0){ src = Wih_c; dst = pk;            ndir = 2; Q = 4; }
  else if (m == 1){ src = Whh_c; dst = pk + PK_WHHC; ndir = 2; Q = 2; }
  else if (m == 2){ src = Wih_n; dst = pk + PK_WIHN; ndir = 6; Q = 4; }
  else { src = Whh_n; dst = pk + PK_WHHN; ndir = 6; Q = 2; }
  const int per = Q * 8192;            // elems per dir: 4c * Q * 4w * 64 * 8
  const int total = ndir * per;
  int e = blockIdx.x * 256 + threadIdx.x;
  if (e >= total) return;
  int sd = e / per, r = e % per;
  int c = r / (Q * 2048); int r2 = r % (Q * 2048);
  int q = r2 / 2048;      int r3 = r2 % 2048;
  int w = r3 >> 9; int lane = (r3 >> 3) & 63; int j = r3 & 7;
  int gate = c * 64 + w * 16 + (lane & 15);
  int col  = q * 32 + (lane >> 4) * 8 + j;
  int D = Q * 32;
  float sc = (c == 2) ? SC_TANH : SC_SIG;   // gate order i,f,g,o
  dst[e] = bf16u(src[((size_t)sd * G4 + gate) * D + col] * sc);
}

// ---------------- Kernel A: content bi-LSTM (T=3, BOTH dirs) + fused Gtab ----
// grid (1875, 3): tile, s.  Each block runs dir0 then dir1 sequentially,
// accumulates the 16-node content tile in LDS, then computes k_gtab's
// 2 sd x 16 MFMA epilogue directly.
__global__ __launch_bounds__(256) void k_content(
    const float* __restrict__ xa, const float* __restrict__ xb,
    const float* __restrict__ xc,
    const unsigned short* __restrict__ pk,
    const float* __restrict__ bih, const float* __restrict__ bhh,
    const float* __restrict__ bih_n, const float* __restrict__ bhh_n,
    unsigned short* __restrict__ content,
    unsigned int* __restrict__ Gtab)
{
  const int tile = blockIdx.x, s = blockIdx.y;
  const float* xs = (s == 0) ? xa : ((s == 1) ? xb : xc);
  const int n0 = tile * 16;
  __shared__ __align__(16) unsigned int xdw[48 * 68];
  __shared__ __align__(16) unsigned short hbuf[2][16 * 72];
  __shared__ __align__(16) unsigned short ctile[16][136];   // padded stride
  const int tid = threadIdx.x;
  const float2* xg2 = reinterpret_cast<const float2*>(xs + (size_t)n0 * 384);
  for (int i = tid; i < 3072; i += 256){
    int node = i / 192, rem = i % 192; int t = rem / 64, c2 = rem % 64;
    float2 v = xg2[i];
    xdw[(t * 16 + node) * 68 + c2] = packbf(v.x, v.y);
  }

  const int lane = tid & 63, w = tid >> 6;
  const int nl = lane & 15, kg = lane >> 4;

  for (int dir = 0; dir < 2; ++dir){
    for (int i = tid; i < 1152; i += 256) hbuf[0][i] = 0;
    __syncthreads();   // covers x staging (iter 0) and hbuf[0] zeroing

    const unsigned short* pkWih = pk + dir * 32768;
    const unsigned short* pkWhh = pk + PK_WHHC + dir * 16384;
    bfrag Bw[4][4], Bh[4][2];
    float bias[4];
    #pragma unroll
    for (int c = 0; c < 4; ++c){
      int gate = c * 64 + w * 16 + nl;
      #pragma unroll
      for (int q = 0; q < 4; ++q)
        Bw[c][q] = ldfrag(pkWih + (((c * 4 + q) * 4 + w) * 64 + lane) * 8);
      Bh[c][0] = ldfrag(pkWhh + (((c * 2 + 0) * 4 + w) * 64 + lane) * 8);
      Bh[c][1] = ldfrag(pkWhh + (((c * 2 + 1) * 4 + w) * 64 + lane) * 8);
      float sc = (c == 2) ? SC_TANH : SC_SIG;
      bias[c] = (bih[dir * G4 + gate] + bhh[dir * G4 + gate]) * sc;
    }

    f32x2 cst2[2] = {f32x2{0,0}, f32x2{0,0}};
    f32x2 hsum2[2] = {f32x2{0,0}, f32x2{0,0}};
    int pp = 0;
    #pragma unroll
    for (int t = 0; t < 3; ++t){
      int tt = dir ? (2 - t) : t;
      f32x4 acc[4];
      #pragma unroll
      for (int c = 0; c < 4; ++c){ f32x4 bv = {bias[c], bias[c], bias[c], bias[c]}; acc[c] = bv; }
      const unsigned short* xrow = reinterpret_cast<const unsigned short*>(&xdw[(tt * 16 + nl) * 68]);
      bfrag ax[4];
      #pragma unroll
      for (int q = 0; q < 4; ++q) ax[q] = ldfrag(xrow + q * 32 + kg * 8);
      #pragma unroll
      for (int c = 0; c < 4; ++c){
        #pragma unroll
        for (int q = 0; q < 4; ++q) acc[c] = mfma16(ax[q], Bw[c][q], acc[c]);
      }
      const unsigned short* hrow = &hbuf[pp][nl * 72];
      bfrag ah0 = ldfrag(hrow + kg * 8);
      bfrag ah1 = ldfrag(hrow + 32 + kg * 8);
      #pragma unroll
      for (int c = 0; c < 4; ++c){
        acc[c] = mfma16(ah0, Bh[c][0], acc[c]);
        acc[c] = mfma16(ah1, Bh[c][1], acc[c]);
      }
      // reads of hbuf[pp] precede writes to hbuf[pp^1]; one barrier publishes.
      #pragma unroll
      for (int p = 0; p < 2; ++p){
        f32x2 gi = {acc[0][2*p], acc[0][2*p+1]};
        f32x2 gf = {acc[1][2*p], acc[1][2*p+1]};
        f32x2 gg = {acc[2][2*p], acc[2][2*p+1]};
        f32x2 go = {acc[3][2*p], acc[3][2*p+1]};
        f32x2 h = lstm_pk(gi, gf, gg, go, cst2[p], hsum2[p]);
        hbuf[pp ^ 1][(kg * 4 + 2*p) * 72 + (w * 16 + nl)]     = bfn(h.x);
        hbuf[pp ^ 1][(kg * 4 + 2*p + 1) * 72 + (w * 16 + nl)] = bfn(h.y);
      }
      __syncthreads();
      pp ^= 1;
    }
    #pragma unroll
    for (int r = 0; r < 4; ++r){
      int n = n0 + kg * 4 + r;
      float hv = (r & 1) ? hsum2[r >> 1].y : hsum2[r >> 1].x;
      unsigned short h16 = bfn(hv * (1.f / 3.f));
      content[((size_t)s * N_NODES + n) * DFEAT + dir * 64 + w * 16 + nl] = h16;
      ctile[kg * 4 + r][dir * 64 + w * 16 + nl] = h16;
    }
    // next dir's hbuf zeroing + its barrier provide the needed sync
  }
  __syncthreads();   // publish ctile for the gtab epilogue

  // ---- fused k_gtab epilogue: Gtab[sd] for sd in {2s, 2s+1} ----
  const unsigned short* crow = &ctile[nl][0];
  bfrag a[4];
  #pragma unroll
  for (int q = 0; q < 4; ++q) a[q] = ldfrag(crow + q * 32 + kg * 8);
  #pragma unroll
  for (int dd = 0; dd < 2; ++dd){
    const int sd = s * 2 + dd;
    const unsigned short* pkW = pk + PK_WIHN + sd * 32768;
    f32x4 acc[4];
    #pragma unroll
    for (int c = 0; c < 4; ++c){
      int gate = c * 64 + w * 16 + nl;
      float sc = (c == 2) ? SC_TANH : SC_SIG;
      float b = (bih_n[sd * G4 + gate] + bhh_n[sd * G4 + gate]) * sc;
      f32x4 bv = {b, b, b, b};
      acc[c] = bv;
    }
    #pragma unroll
    for (int c = 0; c < 4; ++c){
      #pragma unroll
      for (int q = 0; q < 4; ++q){
        bfrag bw = ldfrag(pkW + (((c * 4 + q) * 4 + w) * 64 + lane) * 8);
        acc[c] = mfma16(a[q], bw, acc[c]);
      }
    }
    uint2* g2 = reinterpret_cast<uint2*>(Gtab + (size_t)sd * N_NODES * 128);
    #pragma unroll
    for (int r = 0; r < 4; ++r){
      int n = n0 + kg * 4 + r;
      uint2 v;
      v.x = packbf(acc[0][r], acc[1][r]);
      v.y = packbf(acc[2][r], acc[3][r]);
      g2[(size_t)n * 64 + (w * 16 + nl)] = v;
    }
  }
}

// ---------------- Kernel C: neighbor bi-LSTM over K=10 gathered Gtab rows ----
// R8-exact 256-thread structure (R9's 512-thr dir-merge regressed 28%: 8-wave
// barrier domains + 2 domains/CU + 2 Gtab slices/block all hurt).
// ONE change vs R8: the t-loop barrier is lgkmcnt-only (barrier_lds_only), so
// the t+1 prefetch gathers stay in flight across the barrier instead of being
// drained by __syncthreads' vmcnt(0) every step.
// launch_bounds (256, 4): R7 measured that (256,8) forces VGPR 64->32 and
// spills the ~90-reg working set to scratch. Do not raise.
__global__ __launch_bounds__(256, 4) void k_neigh(
    const unsigned int* __restrict__ Gtab,
    const unsigned short* __restrict__ pk,
    const int* __restrict__ nbr_idx,
    int dparam, size_t nstride,
    unsigned short* __restrict__ nbuf)
{
  const int tile = blockIdx.x, dir = blockIdx.y;
  int s, d;
  if (dparam < 0){ s = blockIdx.z % 3; d = blockIdx.z / 3; }
  else { s = blockIdx.z; d = dparam; }
  unsigned short* nb = nbuf + ((dparam < 0) ? (size_t)d * nstride : (size_t)0);
  const int n0 = tile * 16;
  __shared__ int idxb[160];
  __shared__ __align__(16) unsigned short hbuf[2][16 * 72];
  const int tid = threadIdx.x;
  const int st = idx_stride(nbr_idx);
  const size_t ibase = ((size_t)(s * 3 + d) * N_NODES + n0) * 10;
  // pre-scaled to uint2-row offsets (ridx*64) so gather addr is one 32-bit add
  if (tid < 160) idxb[tid] = nbr_idx[(ibase + tid) * st] * 64;
  for (int i = tid; i < 1152; i += 256) hbuf[0][i] = 0;
  __syncthreads();
  const int lane = tid & 63, w = tid >> 6;
  const int nl = lane & 15, kg = lane >> 4;
  const int lo = w * 16 + nl;
  const int sd = s * 2 + dir;
  const unsigned short* pkW = pk + PK_WHHN + sd * 16384;
  bfrag Bh[4][2];
  #pragma unroll
  for (int c = 0; c < 4; ++c){
    Bh[c][0] = ldfrag(pkW + (((c * 2 + 0) * 4 + w) * 64 + lane) * 8);
    Bh[c][1] = ldfrag(pkW + (((c * 2 + 1) * 4 + w) * 64 + lane) * 8);
  }
  const uint2* gt2 = reinterpret_cast<const uint2*>(Gtab + (size_t)sd * N_NODES * 128);
  uint2 gn[4];
  {
    int ke = dir ? 9 : 0;
    #pragma unroll
    for (int r = 0; r < 4; ++r){
      unsigned off = (unsigned)idxb[(kg * 4 + r) * 10 + ke] + lo;
      gn[r] = gt2[off];
    }
  }
  f32x2 cst2[2] = {f32x2{0,0}, f32x2{0,0}};
  f32x2 hsum2[2] = {f32x2{0,0}, f32x2{0,0}};
  int pp = 0;
  #pragma unroll
  for (int t = 0; t < 10; ++t){
    uint2 cur[4];
    #pragma unroll
    for (int r = 0; r < 4; ++r) cur[r] = gn[r];
    if (t < 9){
      int ke = dir ? (8 - t) : (t + 1);
      #pragma unroll
      for (int r = 0; r < 4; ++r){
        unsigned off = (unsigned)idxb[(kg * 4 + r) * 10 + ke] + lo;
        gn[r] = gt2[off];
      }
    }
    f32x4 acc[4];
    #pragma unroll
    for (int r = 0; r < 4; ++r){
      acc[0][r] = bflo(cur[r].x); acc[1][r] = bfhi(cur[r].x);
      acc[2][r] = bflo(cur[r].y); acc[3][r] = bfhi(cur[r].y);
    }
    const unsigned short* hrow = &hbuf[pp][nl * 72];
    bfrag ah0 = ldfrag(hrow + kg * 8);
    bfrag ah1 = ldfrag(hrow + 32 + kg * 8);
    #pragma unroll
    for (int c = 0; c < 4; ++c){
      acc[c] = mfma16(ah0, Bh[c][0], acc[c]);
      acc[c] = mfma16(ah1, Bh[c][1], acc[c]);
    }
    #pragma unroll
    for (int p = 0; p < 2; ++p){
      f32x2 gi = {acc[0][2*p], acc[0][2*p+1]};
      f32x2 gf = {acc[1][2*p], acc[1][2*p+1]};
      f32x2 gg = {acc[2][2*p], acc[2][2*p+1]};
      f32x2 go = {acc[3][2*p], acc[3][2*p+1]};
      f32x2 h = lstm_pk(gi, gf, gg, go, cst2[p], hsum2[p]);
      hbuf[pp ^ 1][(kg * 4 + 2*p) * 72 + (w * 16 + nl)]     = bfn(h.x);
      hbuf[pp ^ 1][(kg * 4 + 2*p + 1) * 72 + (w * 16 + nl)] = bfn(h.y);
    }
    barrier_lds_only();   // drain ds_writes only; gathers stay in flight
    pp ^= 1;
  }
  #pragma unroll
  for (int r = 0; r < 4; ++r){
    int n = n0 + kg * 4 + r;
    float hv = (r & 1) ? hsum2[r >> 1].y : hsum2[r >> 1].x;
    nb[((size_t)s * N_NODES + n) * DFEAT + dir * 64 + w * 16 + nl] = bfn(hv * 0.1f);
  }
}

// ---------------- Kernel D: attention fusion; output f32 ---------------------
// dparam >= 0: d fixed (looped mode). dparam < 0: d = blockIdx.y, nbuf sliced.
__global__ __launch_bounds__(256) void k_attn(
    const unsigned short* __restrict__ content,
    const unsigned short* __restrict__ nbuf,
    const float* __restrict__ attn_w,
    const float* __restrict__ attn_b,
    int dparam, size_t nstride,
    float* __restrict__ out)
{
  const int d = (dparam < 0) ? (int)blockIdx.y : dparam;
  const unsigned short* nb = nbuf + ((dparam < 0) ? (size_t)d * nstride : (size_t)0);
  const int n = blockIdx.x * 4 + (threadIdx.x >> 6);
  const int lane = threadIdx.x & 63;
  const unsigned int* dh = reinterpret_cast<const unsigned int*>(content) + ((size_t)d * N_NODES + n) * 64;
  const float2* awv = reinterpret_cast<const float2*>(attn_w + d * 256);
  unsigned int udh = dh[lane];
  unsigned int ue[3];
  #pragma unroll
  for (int s_ = 0; s_ < 3; ++s_){
    const unsigned int* np_ = reinterpret_cast<const unsigned int*>(nb) + ((size_t)s_ * N_NODES + n) * 64;
    ue[s_] = np_[lane];
  }
  float2 wl = awv[lane], wh = awv[64 + lane];
  float dh0 = bflo(udh), dh1 = bfhi(udh);
  float p[5];
  p[4] = wl.x * dh0 + wl.y * dh1;
  #pragma unroll
  for (int k = 0; k < 3; ++k){
    p[k] = wh.x * bflo(ue[k]) + wh.y * bfhi(ue[k]);
  }
  p[3] = wh.x * dh0 + wh.y * dh1;
  #pragma unroll
  for (int m = 1; m < 64; m <<= 1){
    #pragma unroll
    for (int jj = 0; jj < 5; ++jj) p[jj] += __shfl_xor(p[jj], m, 64);
  }
  float bias = attn_b[d];
  float logit[4];
  #pragma unroll
  for (int k = 0; k < 4; ++k){
    float x = p[4] + p[k] + bias;
    logit[k] = x > 0.f ? x : 0.01f * x;
  }
  float mx = fmaxf(fmaxf(logit[0], logit[1]), fmaxf(logit[2], logit[3]));
  float ek[4], Z = 0.f;
  #pragma unroll
  for (int k = 0; k < 4; ++k){ ek[k] = __builtin_amdgcn_exp2f(1.442695041f * (logit[k] - mx)); Z += ek[k]; }
  float rz = __builtin_amdgcn_rcpf(Z);
  float o0 = 0.f, o1 = 0.f;
  #pragma unroll
  for (int k = 0; k < 3; ++k){
    float wk = ek[k] * rz;
    o0 += wk * bflo(ue[k]); o1 += wk * bfhi(ue[k]);
  }
  float w3 = ek[3] * rz;
  o0 += w3 * dh0; o1 += w3 * dh1;
  float2 res; res.x = o0; res.y = o1;
  reinterpret_cast<float2*>(out)[((size_t)d * N_NODES + n) * 64 + lane] = res;
}

extern "C" void kernel_launch(void* const* d_in, const int* in_sizes, int n_in,
                              void* d_out, int out_size, void* d_ws, size_t ws_size,
                              hipStream_t stream)
{
  const float* xa    = (const float*)d_in[0];
  const float* xb    = (const float*)d_in[1];
  const float* xc    = (const float*)d_in[2];
  const float* Wih_c = (const float*)d_in[3];
  const float* Whh_c = (const float*)d_in[4];
  const float* bih_c = (const float*)d_in[5];
  const float* bhh_c = (const float*)d_in[6];
  const float* Wih_n = (const float*)d_in[7];
  const float* Whh_n = (const float*)d_in[8];
  const float* bih_n = (const float*)d_in[9];
  const float* bhh_n = (const float*)d_in[10];
  const float* attn_w = (const float*)d_in[11];
  const float* attn_b = (const float*)d_in[12];
  const int*   nbr   = (const int*)d_in[13];
  float* out = (float*)d_out;

  // Fused-d mode needs: content 23.04MB + Gtab 92.16MB + nbuf*3 69.12MB + pk 0.79MB
  const size_t SZ_CONTENT = 23040000;
  const size_t SZ_GTAB    = 92160000;
  const size_t SZ_NBUF    = 23040000;   // one d-slice (3 s * 30000 * 128 * 2B)
  const size_t NSTRIDE    = SZ_NBUF / 2; // in ushorts
  const bool fused = ws_size >= (SZ_CONTENT + SZ_GTAB + 3 * SZ_NBUF + 786432);

  char* ws = (char*)d_ws;
  unsigned short* content = (unsigned short*)ws;
  unsigned int*   Gtab    = (unsigned int*)(ws + SZ_CONTENT);
  unsigned short* nbuf    = (unsigned short*)(ws + SZ_CONTENT + SZ_GTAB);
  unsigned short* pkw     = (unsigned short*)(ws + SZ_CONTENT + SZ_GTAB
                                                 + (fused ? 3 : 1) * SZ_NBUF);

  k_pack<<<dim3(768, 4), 256, 0, stream>>>(Wih_c, Whh_c, Wih_n, Whh_n, pkw);
  k_content<<<dim3(1875, 3), 256, 0, stream>>>(xa, xb, xc, pkw, bih_c, bhh_c,
                                               bih_n, bhh_n, content, Gtab);
  if (fused){
    k_neigh<<<dim3(1875, 2, 9), 256, 0, stream>>>(Gtab, pkw, nbr, -1, NSTRIDE, nbuf);
    k_attn<<<dim3(7500, 3), 256, 0, stream>>>(content, nbuf, attn_w, attn_b, -1, NSTRIDE, out);
  } else {
    for (int d = 0; d < 3; ++d){
      k_neigh<<<dim3(1875, 2, 3), 256, 0, stream>>>(Gtab, pkw, nbr, d, 0, nbuf);
      k_attn<<<dim3(7500), 256, 0, stream>>>(content, nbuf, attn_w, attn_b, d, 0, out);
    }
  }
}